// Round 7
// baseline (609.124 us; speedup 1.0000x reference)
//
#include <hip/hip_runtime.h>
#include <hip/hip_bf16.h>

typedef unsigned short u16;
typedef __attribute__((ext_vector_type(8))) short short8;
typedef __attribute__((ext_vector_type(16))) float f32x16;
typedef __attribute__((ext_vector_type(2))) int int2v;

__device__ __forceinline__ u16 f2b(float f) {  // RNE f32->bf16 bits (proven)
    unsigned int u = __float_as_uint(f);
    return (u16)((u + 0x7fffu + ((u >> 16) & 1u)) >> 16);
}
// packed RNE pair via HIP library (emits v_cvt_pk_bf16_f32): low = a, high = b
__device__ __forceinline__ unsigned pkbf(float a, float b) {
    union { __hip_bfloat162 h; unsigned u; } cv;
    cv.h = __float22bfloat162_rn(make_float2(a, b));
    return cv.u;
}
__device__ __forceinline__ f32x16 zero16() {
    f32x16 z;
#pragma unroll
    for (int q = 0; q < 16; ++q) z[q] = 0.f;
    return z;
}
__device__ __forceinline__ short8 mk8(unsigned w0, unsigned w1, unsigned w2, unsigned w3) {
    union { unsigned u[4]; short8 s; } c;
    c.u[0] = w0; c.u[1] = w1; c.u[2] = w2; c.u[3] = w3;
    return c.s;
}
// rows->k repack: 32x32 C/D tile (16 f32/lane, row=(q&3)+8*(q>>2)+4*half, col=n5)
// -> two K=16 frags (lane = same n5 now meaning row/col of the NEXT mfma, k = old rows).
// f0 covers old rows 0..15 (q0-7), f1 rows 16..31 (q8-15).
__device__ __forceinline__ void repack(const f32x16 a, short8& f0, short8& f1) {
    unsigned x01 = pkbf(a[0], a[1]),  x23 = pkbf(a[2], a[3]);
    unsigned x45 = pkbf(a[4], a[5]),  x67 = pkbf(a[6], a[7]);
    auto r0 = __builtin_amdgcn_permlane32_swap((int)x01, (int)x45, false, false);
    auto r1 = __builtin_amdgcn_permlane32_swap((int)x23, (int)x67, false, false);
    f0 = mk8((unsigned)r0[0], (unsigned)r1[0], (unsigned)r0[1], (unsigned)r1[1]);
    unsigned y01 = pkbf(a[8], a[9]),   y23 = pkbf(a[10], a[11]);
    unsigned y45 = pkbf(a[12], a[13]), y67 = pkbf(a[14], a[15]);
    auto s0 = __builtin_amdgcn_permlane32_swap((int)y01, (int)y45, false, false);
    auto s1 = __builtin_amdgcn_permlane32_swap((int)y23, (int)y67, false, false);
    f1 = mk8((unsigned)s0[0], (unsigned)s1[0], (unsigned)s0[1], (unsigned)s1[1]);
}

#define MFMA32(a, b, c) __builtin_amdgcn_mfma_f32_32x32x16_bf16((a), (b), (c), 0, 0, 0)

// ws (u16): wqk2[8][128][128] @0 : G[a][b] = 0.125 * sum_d Wq[a][h64+d]*Wk[b][h64+d], [a*128+b]
//           wvt[8][64][128] @131072 : Wv_h^T[dv][c]
//           wot[128][512]   @196608 : Wo^T[cout][n]
__global__ void prep_weights(const float* __restrict__ Wq,
                             const float* __restrict__ Wkv,
                             const float* __restrict__ Wo,
                             u16* __restrict__ ws)
{
    const int bid = blockIdx.x, tid = threadIdx.x;
    if (bid < 32) {   // wqk2: block = (h, 32-a-row group g)
        __shared__ float wk_f[128 * 65];   // all Wk rows (b)
        __shared__ float wq_g[32 * 65];    // Wq rows of this a-group
        const int h = bid >> 2, g = bid & 3;
        for (int i = tid; i < 8192; i += 256) {
            int c = i >> 6, d = i & 63;
            wk_f[c * 65 + d] = Wkv[c * 1024 + h * 64 + d];
        }
        for (int i = tid; i < 2048; i += 256) {
            int cl = i >> 6, d = i & 63;
            wq_g[cl * 65 + d] = Wq[(g * 32 + cl) * 512 + h * 64 + d];
        }
        __syncthreads();
        const int bcol = tid & 127, clb = (tid >> 7) * 16;
        float acc[16];
#pragma unroll
        for (int cc = 0; cc < 16; ++cc) acc[cc] = 0.f;
        for (int d = 0; d < 64; ++d) {
            float kb = wk_f[bcol * 65 + d];
#pragma unroll
            for (int cc = 0; cc < 16; ++cc)
                acc[cc] = fmaf(kb, wq_g[(clb + cc) * 65 + d], acc[cc]);
        }
#pragma unroll
        for (int cc = 0; cc < 16; ++cc)
            ws[h * 16384 + (g * 32 + clb + cc) * 128 + bcol] = f2b(0.125f * acc[cc]);
    } else {
        int idx = (bid - 32) * 256 + tid;
        if (idx < 65536) {                 // wvt
            int h = idx >> 13, c = (idx >> 6) & 127, dv = idx & 63;
            ws[131072 + h * 8192 + dv * 128 + c] =
                f2b(Wkv[c * 1024 + 512 + h * 64 + dv]);
        } else {                           // wot
            int j2 = idx - 65536;
            int cout = j2 >> 9, n = j2 & 511;
            ws[196608 + j2] = f2b(Wo[n * 128 + cout]);
        }
    }
}

// WG = 512 threads (8 waves), one (b, blk). HEAD-PER-WAVE, barrier-free head loop.
// Wave w owns head h=w: per j-tile (7 x 32 window rows):
//   t2^T = G_h @ Xwin^T   (A = G[a][b] global frags, B = xj)  -> repack rows(a)->k
//   S^T += t2A @ Xint^T   (B = interior x frags from s_x)
//   p = masked exp(S^T)   -> per-lane row-sum partials + repack rows(j)->k
//   V   = Xwin @ Wv^T     (A = xj, B = wvt)                   -> repack rows(j)->k
//   o^T += vA @ pB        (K accumulated over j-tiles)
// End: cross-half shfl for sums, normalize, o -> o_all LDS. ONE barrier. Then
// epilogue GEMM out^T = Wo^T @ o_all^T (8 waves x 1 tile, K=512) + bias.
// LDS: s_x[224][136] u16 @0 (rows 196..223 zero) | o_all[64][520] u16 @30464
//      | mask_l[7] u32 @byte 127488 | bo_l[128] f32 @byte 127520. Total 128032 B.
// waves_per_eu(2,2): 8 waves/CU -> 256-VGPR budget (regs hold all intermediates).
__global__
__attribute__((amdgpu_flat_work_group_size(512, 512), amdgpu_waves_per_eu(2, 2)))
void halo_attn(const float* __restrict__ xg,
               const u16* __restrict__ wqk2,
               const u16* __restrict__ wvt,
               const u16* __restrict__ wot,
               const float* __restrict__ bo,
               float* __restrict__ outg)
{
    extern __shared__ u16 lds[];
    u16* s_x   = lds;                                        // [224][136]
    u16* o_all = lds + 30464;                                // [64][520]
    unsigned* mask_l = (unsigned*)((char*)lds + 127488);     // 7 u32
    float* bo_l      = (float*)((char*)lds + 127520);        // 128 f32

    const int tid  = threadIdx.x;
    const int w    = tid >> 6;
    const int lane = tid & 63;
    const int n5   = lane & 31;
    const int half = lane >> 5;

    // XCD-swizzle: 128 consecutive logical blocks per XCD (halo L2 reuse)
    const int wg = (blockIdx.x >> 3) + (blockIdx.x & 7) * 128;
    const int b   = wg >> 8;
    const int blk = wg & 255;
    const int by = blk >> 4, bx = blk & 15;
    const int y0 = by * 8 - 3, x0 = bx * 8 - 3;
    const bool inb = (by >= 1) && (by <= 14) && (bx >= 1) && (bx <= 14);

    // ---- zero s_x pad rows 196..223 ----
    for (int t = tid; t < 1904; t += 512)
        ((unsigned*)(s_x + 196 * 136))[t] = 0u;
    // ---- bias to LDS ----
    if (tid < 128) bo_l[tid] = bo[tid];
    // ---- validity bitmasks per j-tile ----
    if (tid < 7) {
        unsigned m = 0;
        for (int bp = 0; bp < 32; ++bp) {
            int j = tid * 32 + bp;
            if (j < 196) {
                int wy = j / 14, wx = j - wy * 14;
                if (inb || (((unsigned)(y0 + wy) < 128u) && ((unsigned)(x0 + wx) < 128u)))
                    m |= (1u << bp);
            }
        }
        mask_l[tid] = m;
    }
    // ---- stage x window [pos][c] bf16; lanes map to gx for coalescing ----
    for (int idx = tid; idx < 32768; idx += 512) {
        int wx = idx & 15, wy = (idx >> 4) & 15, c = idx >> 8;
        if (wx < 14 && wy < 14) {
            int gy = y0 + wy, gx = x0 + wx;
            float val = 0.f;
            if (inb || (((unsigned)gy < 128u) && ((unsigned)gx < 128u)))
                val = xg[((b * 128 + c) * 128 + gy) * 128 + gx];
            s_x[(wy * 14 + wx) * 136 + c] = f2b(val);
        }
    }
    __syncthreads();   // barrier 1 of 2

    const int h = w;   // head-per-wave
    // interior-row address for S's B-frags (lane = col i)
    const int i0 = n5, i1 = 32 + n5;
    const int jq0 = ((i0 >> 3) + 3) * 14 + (i0 & 7) + 3;
    const int jq1 = ((i1 >> 3) + 3) * 14 + (i1 & 7) + 3;

    f32x16 o00 = zero16(), o01 = zero16(), o10 = zero16(), o11 = zero16();
    float sh0 = 0.f, sh1 = 0.f;

#pragma unroll 1
    for (int j7 = 0; j7 < 7; ++j7) {
        const unsigned msk = mask_l[j7];
        // xj: this j-tile's window-x frags (dual-use: B for t2, A for V)
        short8 xj[8];
#pragma unroll
        for (int kc = 0; kc < 8; ++kc)
            xj[kc] = *(const short8*)(s_x + (j7 * 32 + n5) * 136 + kc * 16 + half * 8);

        // ---- t2 + S, software-pipelined over a4 ----
        f32x16 SC0 = zero16(), SC1 = zero16();
        short8 cur[8], nxt[8];
#pragma unroll
        for (int kc = 0; kc < 8; ++kc)
            cur[kc] = *(const short8*)(wqk2 + h * 16384 + n5 * 128 + kc * 16 + half * 8);
#pragma unroll 1
        for (int a4 = 0; a4 < 4; ++a4) {
            if (a4 < 3) {
#pragma unroll
                for (int kc = 0; kc < 8; ++kc)
                    nxt[kc] = *(const short8*)(wqk2 + h * 16384 +
                               ((a4 + 1) * 32 + n5) * 128 + kc * 16 + half * 8);
            }
            f32x16 t2c = zero16();
#pragma unroll
            for (int kc = 0; kc < 8; ++kc) t2c = MFMA32(cur[kc], xj[kc], t2c);
            short8 tA0, tA1;
            repack(t2c, tA0, tA1);
            short8 xb;
            xb = *(const short8*)(s_x + jq0 * 136 + (a4 * 2 + 0) * 16 + half * 8);
            SC0 = MFMA32(tA0, xb, SC0);
            xb = *(const short8*)(s_x + jq0 * 136 + (a4 * 2 + 1) * 16 + half * 8);
            SC0 = MFMA32(tA1, xb, SC0);
            xb = *(const short8*)(s_x + jq1 * 136 + (a4 * 2 + 0) * 16 + half * 8);
            SC1 = MFMA32(tA0, xb, SC1);
            xb = *(const short8*)(s_x + jq1 * 136 + (a4 * 2 + 1) * 16 + half * 8);
            SC1 = MFMA32(tA1, xb, SC1);
#pragma unroll
            for (int kc = 0; kc < 8; ++kc) cur[kc] = nxt[kc];
        }

        // ---- p = masked exp(S^T); per-lane row-sum partials; pack+repack ----
        short8 pB00, pB01, pB10, pB11;
        {
            f32x16 p0;
#pragma unroll
            for (int q = 0; q < 16; ++q) {
                int rq = ((q & 3) + 8 * (q >> 2)) + 4 * half;
                float e = __expf(SC0[q]);
                p0[q] = ((msk >> rq) & 1u) ? e : 0.f;
                sh0 += p0[q];
            }
            repack(p0, pB00, pB01);
            f32x16 p1;
#pragma unroll
            for (int q = 0; q < 16; ++q) {
                int rq = ((q & 3) + 8 * (q >> 2)) + 4 * half;
                float e = __expf(SC1[q]);
                p1[q] = ((msk >> rq) & 1u) ? e : 0.f;
                sh1 += p1[q];
            }
            repack(p1, pB10, pB11);
        }

        // ---- V (both dv chains, weights loaded upfront) ----
        short8 wv0[8], wv1[8];
#pragma unroll
        for (int kc = 0; kc < 8; ++kc) {
            wv0[kc] = *(const short8*)(wvt + h * 8192 + n5 * 128 + kc * 16 + half * 8);
            wv1[kc] = *(const short8*)(wvt + h * 8192 + (32 + n5) * 128 + kc * 16 + half * 8);
        }
        f32x16 vc0 = zero16(), vc1 = zero16();
#pragma unroll
        for (int kc = 0; kc < 8; ++kc) {
            vc0 = MFMA32(xj[kc], wv0[kc], vc0);
            vc1 = MFMA32(xj[kc], wv1[kc], vc1);
        }
        short8 vA00, vA01, vA10, vA11;
        repack(vc0, vA00, vA01);
        repack(vc1, vA10, vA11);

        // ---- PV partial: o^T[dv][i] += v^T @ p (K = this j-tile's 32) ----
        o00 = MFMA32(vA00, pB00, o00); o00 = MFMA32(vA01, pB01, o00);
        o01 = MFMA32(vA00, pB10, o01); o01 = MFMA32(vA01, pB11, o01);
        o10 = MFMA32(vA10, pB00, o10); o10 = MFMA32(vA11, pB01, o10);
        o11 = MFMA32(vA10, pB10, o11); o11 = MFMA32(vA11, pB11, o11);
    } // j7

    // ---- finalize softmax sums (combine halves), normalize, write o_all ----
    const float s0 = sh0 + __shfl_xor(sh0, 32);
    const float s1 = sh1 + __shfl_xor(sh1, 32);
    {
        const f32x16* ot[4] = { &o00, &o01, &o10, &o11 };
#pragma unroll
        for (int t2i = 0; t2i < 4; ++t2i) {
            const int i2 = t2i & 1, dv2 = t2i >> 1;
            const float ss = i2 ? s1 : s0;
            const f32x16 oa = *ot[t2i];
#pragma unroll
            for (int g = 0; g < 4; ++g) {
                unsigned lo = pkbf(oa[4 * g + 0] / ss, oa[4 * g + 1] / ss);
                unsigned hi = pkbf(oa[4 * g + 2] / ss, oa[4 * g + 3] / ss);
                int2v pk; pk[0] = (int)lo; pk[1] = (int)hi;
                *(int2v*)(o_all + (i2 * 32 + n5) * 520 +
                          h * 64 + dv2 * 32 + 8 * g + 4 * half) = pk;
            }
        }
    }
    __syncthreads();   // barrier 2 of 2

    // ---- epilogue: out^T[c][i] = Wo^T @ o_all^T, K=512; 1 tile per wave ----
    {
        const int c4 = w >> 1, i2e = w & 1;
        f32x16 e0 = zero16(), e1 = zero16();
#pragma unroll 1
        for (int kc = 0; kc < 32; kc += 2) {
            short8 wa = *(const short8*)(wot + (c4 * 32 + n5) * 512 + kc * 16 + half * 8);
            short8 ob = *(const short8*)(o_all + (i2e * 32 + n5) * 520 + kc * 16 + half * 8);
            e0 = MFMA32(wa, ob, e0);
            short8 wa2 = *(const short8*)(wot + (c4 * 32 + n5) * 512 + (kc + 1) * 16 + half * 8);
            short8 ob2 = *(const short8*)(o_all + (i2e * 32 + n5) * 520 + (kc + 1) * 16 + half * 8);
            e1 = MFMA32(wa2, ob2, e1);
        }
        const f32x16 res = e0 + e1;
        const int i = i2e * 32 + n5;
        const int gy = by * 8 + (i >> 3), gx = bx * 8 + (i & 7);
#pragma unroll
        for (int q = 0; q < 16; ++q) {
            int rq = ((q & 3) + 8 * (q >> 2)) + 4 * half;
            int ch = c4 * 32 + rq;
            outg[((b * 128 + ch) * 128 + gy) * 128 + gx] = res[q] + bo_l[ch];
        }
    }
}

extern "C" void kernel_launch(void* const* d_in, const int* in_sizes, int n_in,
                              void* d_out, int out_size, void* d_ws, size_t ws_size,
                              hipStream_t stream) {
    const float* x   = (const float*)d_in[0];
    const float* Wq  = (const float*)d_in[1];
    const float* Wkv = (const float*)d_in[2];
    const float* Wo  = (const float*)d_in[3];
    const float* bo  = (const float*)d_in[4];
    float* out = (float*)d_out;
    u16* ws = (u16*)d_ws;   // needs 512 KB

    prep_weights<<<dim3(544), dim3(256), 0, stream>>>(Wq, Wkv, Wo, ws);

    (void)hipFuncSetAttribute((const void*)halo_attn,
                              hipFuncAttributeMaxDynamicSharedMemorySize, 128032);
    halo_attn<<<dim3(1024), dim3(512), 128032, stream>>>(
        x, ws, ws + 131072, ws + 196608, bo, out);
}